// Round 16
// baseline (91.386 us; speedup 1.0000x reference)
//
#include <hip/hip_runtime.h>

// Problem constants (fixed by reference)
#define CIN     32
#define COUT    64
#define OUT_DIM 1024
#define RS4     1024           // float4 per (.,c) row (4096 floats)

// out[b,o,p] = (1/sqrt(32)) * sum_{c,k} x[b,c,4p+k] * w[o,c,4p+k]
//
// v18: DRAM-granule experiment. v13(16.7us)=v17(16.7)=v14/v15(17-19):
// four scheduling structures converge -> scheduling exonerated. Invariant:
// all staged reads were 256B granules at 16KB stride (~3.4 TB/s effective).
// v16's prefetch proved the SAME data read as 1KB-contiguous instructions
// runs at ~6 TB/s. DRAM row-activation arithmetic agrees (256B/row-open vs
// 1KB). v18 reshapes so every staged row is 1KB contiguous:
//   o-tile 4, p-tile 64 f4 (256 floats = 1KB rows), all 16 b, c-chunk 2,
//   16 pipelined iterations, double-buffered LDS (2x40KB = 80KB).
//   w read exactly once (1KB granules); x 16x og-redundant via XCD L2
//   (v3's swizzle: og-siblings of a pg share an XCD; 1MB/XCD L2-resident).
// Compute identical in spirit to v13: LDS-only, per-thread 4b x 4o,
// 2 B/MAC, conflict-free reads; cs split across waves, LDS-reduced
// epilogue, 256B contiguous out stores.
__global__ __launch_bounds__(512, 2) void nolc1d_kernel(
    const float* __restrict__ x,
    const float* __restrict__ w,
    float* __restrict__ out)
{
    // bid = (pg&7) + 8*(og + 16*(pg>>3)): all 16 og-blocks of a pg (which
    // share its 512 KB x slice) land on one XCD; 2 pg per XCD = 1 MB.
    const int bid = blockIdx.x;
    const int xcd = bid & 7;
    const int j   = bid >> 3;
    const int og  = j & 15;                 // o-group 0..15 (4 o each)
    const int pg  = xcd + 8 * (j >> 4);     // patch-group 0..15 (64 f4 each)
    const int o0  = og * 4;
    const int pf0 = pg * 64;                // f4 column base

    const int t    = threadIdx.x;
    const int lane = t & 63;
    const int wv   = t >> 6;                // wave 0..7
    const int q    = lane;                  // f4 column 0..63
    const int bq   = wv & 3;                // b-quad (b = 4bq+bi)
    const int cs   = wv >> 2;               // c-split 0..1 (c%2 within chunk)

    // wls[buf][(ol*2+cl)*64+q] (8 KB/buf); xls[buf][(b*2+cl)*64+q] (32 KB).
    // xls[0] is reused as the 32 KB epilogue reduction buffer.
    __shared__ float4 wls[2][512];
    __shared__ float4 xls[2][2048];

    const float4* __restrict__ x4 = (const float4*)x;
    const float4* __restrict__ w4 = (const float4*)w;

    // Stage c-chunk ci (c = 2ci, 2ci+1): 40 rows x 1 KB (8 w + 32 x) =
    // 40 gload_lds (5/wave). Each instruction: one FULL 1 KB-contiguous
    // row (64 lanes x 16 B); LDS dest wave-uniform + lane*16 (linear).
    auto stage = [&](int buf, int ci) {
        #pragma unroll
        for (int i = 0; i < 5; ++i) {
            const int r = wv * 5 + i;       // 0..39 (wave-uniform)
            if (r < 8) {                    // w rows: ol = r>>1, cl = r&1
                const float4* src =
                    &w4[((size_t)(o0 + (r >> 1)) * CIN + 2 * ci + (r & 1))
                        * RS4 + pf0 + q];
                __builtin_amdgcn_global_load_lds(
                    (const __attribute__((address_space(1))) void*)src,
                    (__attribute__((address_space(3))) void*)&wls[buf][r * 64],
                    16, 0, 0);
            } else {                        // x rows: b = rr>>1, cl = rr&1
                const int rr = r - 8;
                const float4* src =
                    &x4[((size_t)(rr >> 1) * CIN + 2 * ci + (rr & 1))
                        * RS4 + pf0 + q];
                __builtin_amdgcn_global_load_lds(
                    (const __attribute__((address_space(1))) void*)src,
                    (__attribute__((address_space(3))) void*)&xls[buf][rr * 64],
                    16, 0, 0);
            }
        }
    };

    float acc[4][4] = {};                   // [bi][ol], carried over chunks

    stage(0, 0);
    __syncthreads();                        // buffer 0 staged

    #pragma unroll 1
    for (int ci = 0; ci < 16; ++ci) {
        if (ci < 15) stage((ci + 1) & 1, ci + 1);   // prefetch next chunk
        const int buf = ci & 1;
        // compute: LDS-only; this thread's c this chunk: cl = cs.
        float4 xv[4], wq[4];
        #pragma unroll
        for (int bi = 0; bi < 4; ++bi)
            xv[bi] = xls[buf][((bq * 4 + bi) * 2 + cs) * 64 + q];
        #pragma unroll
        for (int ol = 0; ol < 4; ++ol)
            wq[ol] = wls[buf][(ol * 2 + cs) * 64 + q];
        #pragma unroll
        for (int bi = 0; bi < 4; ++bi)
            #pragma unroll
            for (int ol = 0; ol < 4; ++ol)
                acc[bi][ol] += xv[bi].x * wq[ol].x + xv[bi].y * wq[ol].y +
                               xv[bi].z * wq[ol].z + xv[bi].w * wq[ol].w;
        if (ci < 15) __syncthreads();       // handoff (delivery tail)
    }

    // Epilogue: 2-way cs reduction via LDS (cs partner is another wave).
    // red = xls[0] (8192 floats); chunk-15 readers used xls[1]/wls[1], and
    // xls[0]'s last readers finished before iter-14's barrier -> safe.
    float* red = (float*)&xls[0][0];
    #pragma unroll
    for (int bi = 0; bi < 4; ++bi)
        #pragma unroll
        for (int ol = 0; ol < 4; ++ol)
            red[(cs * 64 + (bq * 4 + bi) * 4 + ol) * 64 + q] = acc[bi][ol];
    __syncthreads();

    const float scale = 0.17677669529663687f;  // 1/sqrt(32)
    const int cg = t >> 6;                  // 0..7: combos cg*8..cg*8+7
    #pragma unroll
    for (int jj = 0; jj < 8; ++jj) {
        const int combo = cg * 8 + jj;      // = b*4 + ol
        const float s = red[combo * 64 + q] + red[(64 + combo) * 64 + q];
        out[((size_t)(combo >> 2) * COUT + o0 + (combo & 3)) * OUT_DIM
            + pf0 + q] = s * scale;         // 256 B contiguous per combo
    }
}

extern "C" void kernel_launch(void* const* d_in, const int* in_sizes, int n_in,
                              void* d_out, int out_size, void* d_ws, size_t ws_size,
                              hipStream_t stream) {
    const float* x = (const float*)d_in[0];   // [16][32][4096] fp32
    const float* w = (const float*)d_in[1];   // [64][32][4096] fp32
    float* out = (float*)d_out;               // [16][64][1024] fp32

    nolc1d_kernel<<<dim3(256), dim3(512), 0, stream>>>(x, w, out);
}